// Round 1
// baseline (271.003 us; speedup 1.0000x reference)
//
#include <hip/hip_runtime.h>

// Problem: B=16, C=384, H=W=64, G=48 groups (8 ch/group), K=3 gaussian, sigma=0.5
#define B_   16
#define C_   384
#define H_   64
#define W_   64
#define PLANE (H_ * W_)   // 4096

// v2: float4-per-lane (16 B/lane loads+stores, Guideline 13).
// Lane decomposition: lane = band*16 + c4. band (0..3) owns 8 output rows,
// c4 owns 4 consecutive columns -> one wave covers half a plane (32 rows x 64
// cols). Block = 4 waves = 2 planes; grid = B*C/2 = 3072.
// Displaced rows ybase-1 .. ybase+8 live in a 10-deep float4 ring, all loads
// issued before any consumer. Stores are aligned dwordx4. Loads are dwordx4
// at (ox mod 4) misalignment (4B-aligned; HW unaligned mode) on fully-interior
// strips; the <=2 straddling strips per row take a per-component masked scalar
// path. Horizontal 3-tap: interior taps in-register, edge taps via exactly 2
// shuffles per row executed UNCONDITIONALLY (convergent), patched with
// branchless selects (c4==0 / c4==15 are the true plane edges). No LDS, no
// barriers.
__global__ __launch_bounds__(256) void displace_fused_vec4(
    const float* __restrict__ inp,     // [B,C,H,W]
    const float* __restrict__ offset,  // [G,2] (x,y)
    float* __restrict__ out0,          // displaced
    float* __restrict__ out1)          // blurred
{
    const int tid  = threadIdx.x;
    const int lane = tid & 63;
    const int wv   = tid >> 6;                    // wave 0..3
    const int p    = (blockIdx.x << 1) + (wv >> 1);  // plane in [0, B*C)
    const int g    = (p % C_) >> 3;               // 8 channels per group

    const float ofx = offset[2 * g + 0];
    const float ofy = offset[2 * g + 1];
    const float rx = rintf(ofx);   // half-even == jnp.round; no ties (noise ±0.45)
    const float ry = rintf(ofy);
    const float fx = ofx - rx;
    const float fy = ofy - ry;
    const int ox = (int)rx;
    const int oy = (int)ry;

    // Separable, separately-normalized gaussian: kern[i][j]/sum = wy[i]*wx[j]
    float wx0, wx1, wx2, wy0, wy1, wy2;
    {
        const float dx0 = fx - 1.0f, dx1 = fx, dx2 = fx + 1.0f;
        const float dy0 = fy - 1.0f, dy1 = fy, dy2 = fy + 1.0f;
        wx0 = __expf(-dx0 * dx0 * 2.0f);   // 1/(2*sigma^2) = 2
        wx1 = __expf(-dx1 * dx1 * 2.0f);
        wx2 = __expf(-dx2 * dx2 * 2.0f);
        wy0 = __expf(-dy0 * dy0 * 2.0f);
        wy1 = __expf(-dy1 * dy1 * 2.0f);
        wy2 = __expf(-dy2 * dy2 * 2.0f);
        const float ix = 1.0f / (wx0 + wx1 + wx2);
        const float iy = 1.0f / (wy0 + wy1 + wy2);
        wx0 *= ix; wx1 *= ix; wx2 *= ix;
        wy0 *= iy; wy1 *= iy; wy2 *= iy;
    }

    const int band  = lane >> 4;                  // 0..3, 8 rows each
    const int c4    = lane & 15;                  // column strip
    const int ybase = ((wv & 1) << 5) + (band << 3);  // first output row
    const int x0    = c4 << 2;                    // first output column
    const int sx0   = x0 - ox;                    // first source column
    const bool fullv = (sx0 >= 0) & (sx0 <= W_ - 4);  // vec4 stays in-row

    const float* __restrict__ plane = inp + (size_t)p * PLANE;

    // Displaced rows ybase-1 .. ybase+8. Rows outside [0,64) are conv
    // zero-pad; rows whose source (y-oy) is OOB are displacement zero-pad.
    float4 v[10];
    #pragma unroll
    for (int k = 0; k < 10; ++k) {
        const int y  = ybase - 1 + k;
        const int sy = y - oy;
        float4 q = make_float4(0.0f, 0.0f, 0.0f, 0.0f);
        if (((unsigned)y < (unsigned)H_) & ((unsigned)sy < (unsigned)H_)) {
            const float* __restrict__ row = plane + sy * W_;
            if (fullv) {
                q = *reinterpret_cast<const float4*>(row + sx0);  // 4B-aligned ok
            } else {
                // straddling / fully-OOB strips: per-component masked scalars
                if ((unsigned)(sx0 + 0) < (unsigned)W_) q.x = row[sx0 + 0];
                if ((unsigned)(sx0 + 1) < (unsigned)W_) q.y = row[sx0 + 1];
                if ((unsigned)(sx0 + 2) < (unsigned)W_) q.z = row[sx0 + 2];
                if ((unsigned)(sx0 + 3) < (unsigned)W_) q.w = row[sx0 + 3];
            }
        }
        v[k] = q;
    }

    float* __restrict__ o0 = out0 + (size_t)p * PLANE + ybase * W_ + x0;
    float* __restrict__ o1 = out1 + (size_t)p * PLANE + ybase * W_ + x0;

    // Horizontal 3-tap per displaced row; out0 stores interleaved so v[k]
    // dies early (register pressure). Shuffles run with ALL lanes active;
    // band-crossing lanes (c4==0/15) are the genuine plane edges -> patched
    // to the conv zero-pad with branchless selects.
    float4 h[10];
    #pragma unroll
    for (int k = 0; k < 10; ++k) {
        const float4 q  = v[k];
        const float  su = __shfl_up(q.w, 1, 64);    // unconditional
        const float  sd = __shfl_down(q.x, 1, 64);  // unconditional
        const float  L  = (c4 == 0)  ? 0.0f : su;
        const float  R  = (c4 == 15) ? 0.0f : sd;
        float4 t;
        t.x = L   * wx0 + q.x * wx1 + q.y * wx2;
        t.y = q.x * wx0 + q.y * wx1 + q.z * wx2;
        t.z = q.y * wx0 + q.z * wx1 + q.w * wx2;
        t.w = q.z * wx0 + q.w * wx1 + R   * wx2;
        h[k] = t;
        if (k >= 1 && k <= 8) {
            *reinterpret_cast<float4*>(o0 + (k - 1) * W_) = q;  // displaced out
        }
    }

    // Vertical 3-tap, aligned vec4 stores.
    #pragma unroll
    for (int r = 0; r < 8; ++r) {
        float4 b;
        b.x = h[r].x * wy0 + h[r + 1].x * wy1 + h[r + 2].x * wy2;
        b.y = h[r].y * wy0 + h[r + 1].y * wy1 + h[r + 2].y * wy2;
        b.z = h[r].z * wy0 + h[r + 1].z * wy1 + h[r + 2].z * wy2;
        b.w = h[r].w * wy0 + h[r + 1].w * wy1 + h[r + 2].w * wy2;
        *reinterpret_cast<float4*>(o1 + r * W_) = b;
    }
}

extern "C" void kernel_launch(void* const* d_in, const int* in_sizes, int n_in,
                              void* d_out, int out_size, void* d_ws, size_t ws_size,
                              hipStream_t stream) {
    const float* inp    = (const float*)d_in[0];
    const float* offset = (const float*)d_in[1];
    float* out0 = (float*)d_out;
    float* out1 = out0 + (size_t)B_ * C_ * PLANE;
    displace_fused_vec4<<<(B_ * C_) / 2, 256, 0, stream>>>(inp, offset, out0, out1);
}